// Round 8
// baseline (1451.304 us; speedup 1.0000x reference)
//
#include <hip/hip_runtime.h>
#include <hip/hip_bf16.h>

// ---- problem constants ----
#define B_   16384
#define H_   128
#define C_   4
#define L_   6
#define O_   1024
#define G3H  384
#define CB   (C_ * B_)
#define CBH  (C_ * B_ * H_)

typedef __hip_bfloat16 bf16;
using bf16x8  = __attribute__((ext_vector_type(8))) __bf16;
using bf16x4  = __attribute__((ext_vector_type(4))) __bf16;
using floatx4 = __attribute__((ext_vector_type(4))) float;

__device__ __forceinline__ bf16 f2bf(float x) { return __float2bfloat16(x); }
__device__ __forceinline__ float bf2f(bf16 x) { return __bfloat162float(x); }

__device__ __forceinline__ floatx4 mfma16(bf16x8 a, bf16x8 b, floatx4 c) {
  return __builtin_amdgcn_mfma_f32_16x16x32_bf16(a, b, c, 0, 0, 0);
}

__device__ __forceinline__ bf16x8 load8(const bf16* p) { return *(const bf16x8*)p; }
__device__ __forceinline__ bf16x8 load8(const float* p) {
  const float4 a = *(const float4*)p;
  const float4 b = *(const float4*)(p + 4);
  bf16x8 r;
  r[0] = (__bf16)a.x; r[1] = (__bf16)a.y; r[2] = (__bf16)a.z; r[3] = (__bf16)a.w;
  r[4] = (__bf16)b.x; r[5] = (__bf16)b.y; r[6] = (__bf16)b.z; r[7] = (__bf16)b.w;
  return r;
}

__device__ __forceinline__ float sigmoidf_(float x) {
  return 1.f / (1.f + __expf(-x));
}
__device__ __forceinline__ float tanhf_(float x) {
  float e = __expf(2.f * x);
  return 1.f - 2.f / (e + 1.f);
}

// single-launch weight conversion: 7 contiguous dst segments (4-elem units)
struct Cvt7 {
  const float* src[7];
  long start4[8];
};
__global__ __launch_bounds__(256) void cvt7_kernel(Cvt7 a, bf16* __restrict__ dst) {
  long i4 = (long)blockIdx.x * 256 + threadIdx.x;
  if (i4 >= a.start4[7]) return;
  int s = 0;
#pragma unroll
  for (int k = 1; k < 7; ++k)
    if (i4 >= a.start4[k]) s = k;
  const float4 v = ((const float4*)a.src[s])[i4 - a.start4[s]];
  bf16x4 o;
  o[0] = (__bf16)v.x; o[1] = (__bf16)v.y; o[2] = (__bf16)v.z; o[3] = (__bf16)v.w;
  ((bf16x4*)dst)[i4] = o;
}

// ---------------------------------------------------------------------------
// Persistent whole-network kernel.
// Block = 16 batch elems x 4 cells = 64 rows, 256 threads (wave w = cell w).
// All 6 layers + head run in-block; cross-layer state (x = prev hn) lives in
// LDS (bf16) and pre-gate hn lives in 32 regs/thread. No grid sync needed:
// every dependency (gi on hn_prev same (c,b); attention across cells of same
// b; gate row-local; head on cell-0 rows) is block-local.
//
// LDS regions (69632 B total -> 2 blocks/CU with __launch_bounds__(256,2)):
//   D[49152]: phase-aliased:
//     stage/GEMM1: h_bf16 [0,16K) | hn_bf16 [16K,32K)
//     qkv:         Q [0,16K) | K [16K,32K) | V [32K,48K)
//     attn PV out: o_raw [0,16K)  (Q dead after QK^T barrier)
//     oproj out:   o2_s f32 [64][132] [0,33792)  (o_raw hoisted to regs first)
//   X[16384]: current-layer x (bf16, swizzled); rewritten each phase D.
//   p_s[4096]: attention probs [16 b][4 hd][4 qc][4 kc].
// All rows stored swizzled: byte ^= (row&7)<<4 within 256B rows.
// 9 barriers/layer separate every aliasing window (B0..B8 comments).
// ---------------------------------------------------------------------------
struct P {
  const int* tok; const float* h; const float* emb;
  const bf16 *wih0, *whh0, *wih, *whh, *ainw, *aoutw, *headw;
  const float *bih0, *bhh0, *bih, *bhh, *ainb, *aoutb, *lng, *lnb, *gw, *gb, *headb;
  float *y, *hn;
};

__global__ __launch_bounds__(256, 2) void gridrnn(P p) {
  __shared__ __align__(16) char D[49152];
  __shared__ __align__(16) char X[16384];
  __shared__ __align__(16) float p_s[1024];

  const int tid = threadIdx.x;
  const int wave = tid >> 6, lane = tid & 63;
  const int sub = lane & 15, quad = lane >> 4;
  const int b0 = blockIdx.x * 16;

  // ---- initial x staging: layer-0 cell-0 rows = bf16(emb[tok]) ----
  {
    const int row = tid >> 4, ch = tid & 15;  // rows 0..15 x 16 chunks
    const int tk = p.tok[b0 + row];
    bf16x8 v = load8(p.emb + (long)tk * 128 + ch * 8);
    *(bf16x8*)(X + ((row * 256 + ch * 16) ^ ((row & 7) << 4))) = v;
  }

  float hnreg[8][4];  // pre-gate hn: rows quad*4+r of cell=wave, cols pp*16+sub

#pragma unroll 1
  for (int l = 0; l < L_; ++l) {
    __syncthreads();  // B0: prev phase D (o2_s reads / X writes) complete
    const float* hl = p.h + (long)l * CBH;
    // ---- stage h[l] -> D[0,16K) ----
#pragma unroll
    for (int i = 0; i < 4; ++i) {
      const int idx = i * 256 + tid;
      const int row = idx >> 4, ch = idx & 15;
      const long grow = (long)(row >> 4) * B_ + b0 + (row & 15);
      bf16x8 v = load8(hl + grow * H_ + ch * 8);
      *(bf16x8*)(D + ((row * 256 + ch * 16) ^ ((row & 7) << 4))) = v;
    }
    __syncthreads();  // B1

    const bool has_gi = (l > 0) || (wave == 0);
    const bf16* Wh = (l == 0 ? p.whh0 : p.whh + (long)(l - 1) * C_ * G3H * H_) +
                     (long)wave * G3H * H_;
    const bf16* Wi = (l == 0)
                         ? p.wih0
                         : p.wih + (long)(l - 1) * C_ * G3H * H_ + (long)wave * G3H * H_;
    const float* bh = (l == 0 ? p.bhh0 : p.bhh + (long)(l - 1) * C_ * G3H) + wave * G3H;
    const float* bi = (l == 0 ? p.bih0 : p.bih + (long)(l - 1) * C_ * G3H) + wave * G3H;

    // A-fragments for this wave's cell, loaded ONCE per layer
    const int arow = wave * 16 + sub;
    bf16x8 hfr[4], xfr[4];
#pragma unroll
    for (int kc = 0; kc < 4; ++kc)
      hfr[kc] = *(const bf16x8*)(D + ((arow * 256 + kc * 64 + quad * 16) ^
                                      ((arow & 7) << 4)));
    if (has_gi) {
#pragma unroll
      for (int kc = 0; kc < 4; ++kc)
        xfr[kc] = *(const bf16x8*)(X + ((arow * 256 + kc * 64 + quad * 16) ^
                                        ((arow & 7) << 4)));
    }

    // ---- GEMM1 (gi+gh) + GRU: 8 col-passes of 16 ----
#pragma unroll
    for (int pp = 0; pp < 8; ++pp) {
      const int colr = pp * 16 + sub;
      bf16x8 wfr[3][4];
#pragma unroll
      for (int g = 0; g < 3; ++g) {
        const bf16* Wg = Wh + (long)(g * 128 + colr) * H_ + quad * 8;
#pragma unroll
        for (int kc = 0; kc < 4; ++kc) wfr[g][kc] = load8(Wg + kc * 32);
      }
      floatx4 ar = {0.f, 0.f, 0.f, 0.f}, az = {0.f, 0.f, 0.f, 0.f};
      floatx4 anh = {0.f, 0.f, 0.f, 0.f}, ani = {0.f, 0.f, 0.f, 0.f};
      if (has_gi) {
        bf16x8 wif[3][4];
#pragma unroll
        for (int g = 0; g < 3; ++g) {
          const bf16* Wg = Wi + (long)(g * 128 + colr) * H_ + quad * 8;
#pragma unroll
          for (int kc = 0; kc < 4; ++kc) wif[g][kc] = load8(Wg + kc * 32);
        }
#pragma unroll
        for (int kc = 0; kc < 4; ++kc) {
          ar  = mfma16(xfr[kc], wif[0][kc], ar);   // r: gi+gh co-accumulated
          az  = mfma16(xfr[kc], wif[1][kc], az);   // z: gi+gh co-accumulated
          ani = mfma16(xfr[kc], wif[2][kc], ani);  // n: kept separate
        }
      }
#pragma unroll
      for (int kc = 0; kc < 4; ++kc) {
        ar  = mfma16(hfr[kc], wfr[0][kc], ar);
        az  = mfma16(hfr[kc], wfr[1][kc], az);
        anh = mfma16(hfr[kc], wfr[2][kc], anh);
      }

      const float bir = bi[colr],        bhr = bh[colr];
      const float biz = bi[128 + colr],  bhz = bh[128 + colr];
      const float bin_ = bi[256 + colr], bhn = bh[256 + colr];
#pragma unroll
      for (int r = 0; r < 4; ++r) {
        const int lrow = wave * 16 + quad * 4 + r;
        const long grow = (long)wave * B_ + b0 + quad * 4 + r;
        float rg = sigmoidf_(ar[r] + bir + bhr);
        float zg = sigmoidf_(az[r] + biz + bhz);
        float ng = tanhf_(ani[r] + bin_ + rg * (anh[r] + bhn));
        float hv = hl[grow * H_ + colr];
        float hnv = (1.f - zg) * ng + zg * hv;
        hnreg[pp][r] = hnv;
        *(bf16*)(D + 16384 + ((lrow * 256 + colr * 2) ^ ((lrow & 7) << 4))) = f2bf(hnv);
      }
    }
    __syncthreads();  // B2: hn_bf16 complete

    // ---- qkv A-frag hoist (all 64 rows) ----
    bf16x8 af[4][4];
#pragma unroll
    for (int rt = 0; rt < 4; ++rt)
#pragma unroll
      for (int kc = 0; kc < 4; ++kc) {
        const int lrow = rt * 16 + sub;
        af[rt][kc] = *(const bf16x8*)(D + 16384 +
                      ((lrow * 256 + kc * 64 + quad * 16) ^ ((lrow & 7) << 4)));
      }
    __syncthreads();  // B3: hoist done; D free for Q/K/V

    // ---- qkv GEMM -> Q [0,16K) K [16K,32K) V [32K,48K) ----
    {
      const bf16* ainw_l = p.ainw + (long)l * G3H * H_;
      const float* ainb_l = p.ainb + (long)l * G3H;
#pragma unroll
      for (int t = 0; t < 6; ++t) {
        const int col = wave * 96 + t * 16 + sub;
        const bf16* Wp = ainw_l + (long)col * H_ + quad * 8;
        bf16x8 wf[4];
#pragma unroll
        for (int kc = 0; kc < 4; ++kc) wf[kc] = load8(Wp + kc * 32);
        const float bv = ainb_l[col];
        const int tile = (col >> 7) * 16384;
        const int lcol = col & 127;
#pragma unroll
        for (int rt = 0; rt < 4; ++rt) {
          floatx4 acc = {0.f, 0.f, 0.f, 0.f};
#pragma unroll
          for (int kc = 0; kc < 4; ++kc) acc = mfma16(af[rt][kc], wf[kc], acc);
#pragma unroll
          for (int r = 0; r < 4; ++r) {
            const int lrow = rt * 16 + quad * 4 + r;
            *(bf16*)(D + tile + ((lrow * 256 + lcol * 2) ^ ((lrow & 7) << 4))) =
                f2bf(acc[r] + bv);
          }
        }
      }
    }
    __syncthreads();  // B4: Q/K/V ready

    // ---- QK^T (MFMA) + softmax -> p_s ----
    {
      const int hd = wave;
#pragma unroll
      for (int bg = 0; bg < 4; ++bg) {
        const int rr = (sub & 3) * 16 + bg * 4 + (sub >> 2);
        const int soff = ((rr * 256 + hd * 64 + quad * 16) ^ ((rr & 7) << 4));
        bf16x8 qa = *(const bf16x8*)(D + soff);
        bf16x8 kb = *(const bf16x8*)(D + 16384 + soff);
        floatx4 sc = {0.f, 0.f, 0.f, 0.f};
        sc = mfma16(qa, kb, sc);
        float pr[4];
#pragma unroll
        for (int r = 0; r < 4; ++r) {
          float s = sc[r] * 0.17677669529663687f;  // 1/sqrt(32)
          float m = fmaxf(s, __shfl_xor(s, 1));
          m = fmaxf(m, __shfl_xor(m, 2));
          float e = __expf(s - m);
          float ss = e + __shfl_xor(e, 1);
          ss += __shfl_xor(ss, 2);
          pr[r] = e / ss;
        }
        if (quad == (sub >> 2)) {
          const int bl = bg * 4 + quad;
#pragma unroll
          for (int r = 0; r < 4; ++r)
            p_s[((bl * 4 + hd) * 4 + r) * 4 + (sub & 3)] = pr[r];
        }
      }
    }
    __syncthreads();  // B5: p_s ready; Q dead

    // ---- PV -> o_raw [0,16K) (reads V [32K,48K)) ----
#pragma unroll
    for (int i = 0; i < 4; ++i) {
      const int m = i * 256 + tid;
      const int row = m >> 4, ch = m & 15;
      const int qc = row >> 4, bj = row & 15, hd = ch >> 2;
      float acc[8];
#pragma unroll
      for (int j = 0; j < 8; ++j) acc[j] = 0.f;
#pragma unroll
      for (int kc = 0; kc < 4; ++kc) {
        const float pv = p_s[((bj * 4 + hd) * 4 + qc) * 4 + kc];
        const int vrow = kc * 16 + bj;
        bf16x8 vv = *(const bf16x8*)(D + 32768 +
                     ((vrow * 256 + ch * 16) ^ ((vrow & 7) << 4)));
#pragma unroll
        for (int j = 0; j < 8; ++j) acc[j] += pv * (float)vv[j];
      }
      bf16x8 ov;
#pragma unroll
      for (int j = 0; j < 8; ++j) ov[j] = (__bf16)acc[j];
      *(bf16x8*)(D + ((row * 256 + ch * 16) ^ ((row & 7) << 4))) = ov;
    }
    __syncthreads();  // B6: o_raw ready

    // ---- oproj A-frag hoist ----
    bf16x8 af2[4][4];
#pragma unroll
    for (int rt = 0; rt < 4; ++rt)
#pragma unroll
      for (int kc = 0; kc < 4; ++kc) {
        const int lrow = rt * 16 + sub;
        af2[rt][kc] = *(const bf16x8*)(D +
                       ((lrow * 256 + kc * 64 + quad * 16) ^ ((lrow & 7) << 4)));
      }
    __syncthreads();  // B7: hoist done; D free for o2_s

    // ---- oproj GEMM -> o2_s f32 [64][132] at D[0,33792) ----
    float* o2 = (float*)D;
    {
      const bf16* aoutw_l = p.aoutw + (long)l * H_ * H_;
      const float* aoutb_l = p.aoutb + (long)l * H_;
#pragma unroll
      for (int p2 = 0; p2 < 2; ++p2) {
        const int col = wave * 32 + p2 * 16 + sub;
        const bf16* Wp = aoutw_l + (long)col * H_ + quad * 8;
        bf16x8 wf[4];
#pragma unroll
        for (int kc = 0; kc < 4; ++kc) wf[kc] = load8(Wp + kc * 32);
        const float bv = aoutb_l[col];
#pragma unroll
        for (int rt = 0; rt < 4; ++rt) {
          floatx4 acc = {0.f, 0.f, 0.f, 0.f};
#pragma unroll
          for (int kc = 0; kc < 4; ++kc) acc = mfma16(af2[rt][kc], wf[kc], acc);
#pragma unroll
          for (int r = 0; r < 4; ++r)
            o2[(rt * 16 + quad * 4 + r) * 132 + col] = acc[r] + bv;
        }
      }
    }
    __syncthreads();  // B8: o2_s ready

    // ---- LN + gate + blend (hn pre-gate from regs) ----
    {
      float o2v[8][4];
#pragma unroll
      for (int pi = 0; pi < 8; ++pi)
#pragma unroll
        for (int r = 0; r < 4; ++r)
          o2v[pi][r] = o2[(wave * 16 + quad * 4 + r) * 132 + pi * 16 + sub];

      float mu[4], rs[4];
#pragma unroll
      for (int r = 0; r < 4; ++r) {
        float s = 0.f;
#pragma unroll
        for (int pi = 0; pi < 8; ++pi) s += o2v[pi][r];
        s += __shfl_xor(s, 1); s += __shfl_xor(s, 2);
        s += __shfl_xor(s, 4); s += __shfl_xor(s, 8);
        mu[r] = s * (1.f / 128.f);
      }
#pragma unroll
      for (int r = 0; r < 4; ++r) {
        float vs = 0.f;
#pragma unroll
        for (int pi = 0; pi < 8; ++pi) {
          float d = o2v[pi][r] - mu[r];
          vs += d * d;
        }
        vs += __shfl_xor(vs, 1); vs += __shfl_xor(vs, 2);
        vs += __shfl_xor(vs, 4); vs += __shfl_xor(vs, 8);
        rs[r] = rsqrtf(vs * (1.f / 128.f) + 1e-5f);
      }

      const float* lngl = p.lng + l * H_;
      const float* lnbl = p.lnb + l * H_;
      const float* gwl  = p.gw + l * 2 * H_;
      float msg[8][4];
      float gpp[4] = {0.f, 0.f, 0.f, 0.f};
#pragma unroll
      for (int pi = 0; pi < 8; ++pi) {
        const int c = pi * 16 + sub;
        const float gv = lngl[c], bv2 = lnbl[c];
        const float g1 = gwl[c], g2 = gwl[128 + c];
#pragma unroll
        for (int r = 0; r < 4; ++r) {
          float mval = (o2v[pi][r] - mu[r]) * rs[r] * gv + bv2;
          msg[pi][r] = mval;
          gpp[r] += hnreg[pi][r] * g1 + mval * g2;
        }
      }
      const float gbl = p.gb[l];
      float gt[4];
#pragma unroll
      for (int r = 0; r < 4; ++r) {
        float s = gpp[r];
        s += __shfl_xor(s, 1); s += __shfl_xor(s, 2);
        s += __shfl_xor(s, 4); s += __shfl_xor(s, 8);
        gt[r] = sigmoidf_(s + gbl);
      }
      float* hnl = p.hn + (long)l * CBH;
#pragma unroll
      for (int pi = 0; pi < 8; ++pi) {
        const int c = pi * 16 + sub;
#pragma unroll
        for (int r = 0; r < 4; ++r) {
          const int lrow = wave * 16 + quad * 4 + r;
          const long grow = (long)wave * B_ + b0 + quad * 4 + r;
          float outv = (1.f - gt[r]) * hnreg[pi][r] + gt[r] * msg[pi][r];
          hnl[grow * H_ + c] = outv;
          *(bf16*)(X + ((lrow * 256 + c * 2) ^ ((lrow & 7) << 4))) = f2bf(outv);
        }
      }
    }
  }  // layer loop

  __syncthreads();  // final phase D complete; X holds layer-5 hn bf16

  // ---- head: y[b,:] = hn[5,0,b,:] @ headw^T + headb (cell-0 rows 0..15) ----
  {
    bf16x8 afh[4];
#pragma unroll
    for (int kc = 0; kc < 4; ++kc)
      afh[kc] = *(const bf16x8*)(X + ((sub * 256 + kc * 64 + quad * 16) ^
                                      ((sub & 7) << 4)));
#pragma unroll
    for (int t = 0; t < 16; ++t) {
      const int col = wave * 256 + t * 16 + sub;
      const bf16* Wp = p.headw + (long)col * H_ + quad * 8;
      bf16x8 wf[4];
#pragma unroll
      for (int kc = 0; kc < 4; ++kc) wf[kc] = load8(Wp + kc * 32);
      const float bv = p.headb[col];
      floatx4 acc = {0.f, 0.f, 0.f, 0.f};
#pragma unroll
      for (int kc = 0; kc < 4; ++kc) acc = mfma16(afh[kc], wf[kc], acc);
#pragma unroll
      for (int r = 0; r < 4; ++r)
        p.y[(long)(b0 + quad * 4 + r) * O_ + col] = acc[r] + bv;
    }
  }
}

extern "C" void kernel_launch(void* const* d_in, const int* in_sizes, int n_in,
                              void* d_out, int out_size, void* d_ws, size_t ws_size,
                              hipStream_t stream) {
  const int*   tokens = (const int*)d_in[0];
  const float* h      = (const float*)d_in[1];
  const float* emb    = (const float*)d_in[2];
  const float* wih0c0 = (const float*)d_in[3];
  const float* bih0   = (const float*)d_in[5];
  const float* whh0   = (const float*)d_in[6];
  const float* bhh0   = (const float*)d_in[7];
  const float* wih    = (const float*)d_in[8];
  const float* whh    = (const float*)d_in[9];
  const float* bih    = (const float*)d_in[10];
  const float* bhh    = (const float*)d_in[11];
  const float* ainw   = (const float*)d_in[12];
  const float* ainb   = (const float*)d_in[13];
  const float* aoutw  = (const float*)d_in[14];
  const float* aoutb  = (const float*)d_in[15];
  const float* lng    = (const float*)d_in[16];
  const float* lnb    = (const float*)d_in[17];
  const float* gw     = (const float*)d_in[18];
  const float* gb     = (const float*)d_in[19];
  const float* headw  = (const float*)d_in[20];
  const float* headb  = (const float*)d_in[21];

  float* y_out  = (float*)d_out;                 // (B, O)
  float* hn_out = (float*)d_out + (long)B_ * O_; // (L, C, B, H)

  // workspace: bf16 weights only
  bf16* wp = (bf16*)d_ws;
  bf16* wih0bf  = wp;                  wp += 49152;   // 384*128
  bf16* whh0bf  = wp;                  wp += 196608;  // 4*384*128
  bf16* wihbf   = wp;                  wp += 983040;  // 5*4*384*128
  bf16* whhbf   = wp;                  wp += 983040;
  bf16* ainwbf  = wp;                  wp += 294912;  // 6*384*128
  bf16* aoutwbf = wp;                  wp += 98304;   // 6*128*128
  bf16* headwbf = wp;                  wp += 131072;  // 1024*128

  dim3 blk(256);
  {
    Cvt7 a;
    const float* srcs[7] = {wih0c0, whh0, wih, whh, ainw, aoutw, headw};
    const long lens[7] = {49152, 196608, 983040, 983040, 294912, 98304, 131072};
    long cum = 0;
    for (int i = 0; i < 7; ++i) { a.src[i] = srcs[i]; a.start4[i] = cum / 4; cum += lens[i]; }
    a.start4[7] = cum / 4;
    const long n4 = cum / 4;
    cvt7_kernel<<<(int)((n4 + 255) / 256), blk, 0, stream>>>(a, wih0bf);
  }

  P pp;
  pp.tok = tokens; pp.h = h; pp.emb = emb;
  pp.wih0 = wih0bf; pp.whh0 = whh0bf; pp.wih = wihbf; pp.whh = whhbf;
  pp.ainw = ainwbf; pp.aoutw = aoutwbf; pp.headw = headwbf;
  pp.bih0 = bih0; pp.bhh0 = bhh0; pp.bih = bih; pp.bhh = bhh;
  pp.ainb = ainb; pp.aoutb = aoutb; pp.lng = lng; pp.lnb = lnb;
  pp.gw = gw; pp.gb = gb; pp.headb = headb;
  pp.y = y_out; pp.hn = hn_out;

  gridrnn<<<B_ / 16, blk, 0, stream>>>(pp);
}